// Round 4
// baseline (248.470 us; speedup 1.0000x reference)
//
#include <hip/hip_runtime.h>

// FANeuron two-pass:
//  K1 (scan): sequential per-chain recurrence, compute-only, stores exact
//             (ema, refc) state entering every L_CHUNK-step chunk.
//             LDS-tiled: 64-thread block = 64 chains (one b, 64 features).
//             Per 64-step tile: 16 coalesced dwordx4 loads (issued one tile
//             ahead, latency hidden under compute) -> regs -> LDS, then each
//             lane streams its column from LDS. Single wave: no barriers.
//  K2 (emit): one thread per (chain, chunk) replays its chunk bit-exactly
//             from the seeded state and writes va_trace + spikes.

#define L_CHUNK 256
#define TS 64          // timesteps per K1 tile
#define K2_UNROLL 8

// General step (separately-rounded f32, contract off at kernel level).
#define FA_STEP_GEN(XT, IS_FIRST)                                  \
    do {                                                           \
        float xt_ = (XT);                                          \
        if (IS_FIRST) {                                            \
            ema = xt_;                                             \
        } else {                                                   \
            float d1_ = xt_ - ema;                                 \
            float am_ = alpha * d1_;                               \
            ema = ema + am_;                                       \
        }                                                          \
        float d2_ = xt_ - ema;                                     \
        float av_ = Af * d2_;                                      \
        va_cand_ = vbf - av_;                                      \
        float dv_ = va_cand_ - vbf;                                \
        cross_ = fabsf(dv_) >= thf;                                \
        in_ref_ = refc > 0;                                        \
        fired_ = cross_ && !in_ref_;                               \
        int rd_ = refc - 1;                                        \
        rd_ = rd_ < 0 ? 0 : rd_;                                   \
        refc = fired_ ? rs : rd_;                                  \
    } while (0)

// K1 inner step, fast path (gain==1, A==1, vb==0): bit-exact reduction.
#define K1_STEP_FAST(XV)                                           \
    do {                                                           \
        float xv_ = (XV);                                          \
        float d1_ = xv_ - ema;                                     \
        float am_ = alpha * d1_;                                   \
        ema = ema + am_;                                           \
        float d2_ = xv_ - ema;                                     \
        bool cross_ = fabsf(d2_) >= thf;                           \
        bool in_ref_ = refc > 0;                                   \
        bool fired_ = cross_ && !in_ref_;                          \
        int rd_ = refc - 1;                                        \
        rd_ = rd_ < 0 ? 0 : rd_;                                   \
        refc = fired_ ? rs : rd_;                                  \
    } while (0)

// K1 inner step, general params (xt = raw * gain applied by caller).
#define K1_STEP_GEN(XT)                                            \
    do {                                                           \
        float xt_ = (XT);                                          \
        float d1_ = xt_ - ema;                                     \
        float am_ = alpha * d1_;                                   \
        ema = ema + am_;                                           \
        float d2_ = xt_ - ema;                                     \
        float av_ = Af * d2_;                                      \
        float vc_ = vbf - av_;                                     \
        float dv_ = vc_ - vbf;                                     \
        bool cross_ = fabsf(dv_) >= thf;                           \
        bool in_ref_ = refc > 0;                                   \
        bool fired_ = cross_ && !in_ref_;                          \
        int rd_ = refc - 1;                                        \
        rd_ = rd_ < 0 ? 0 : rd_;                                   \
        refc = fired_ ? rs : rd_;                                  \
    } while (0)

__global__ __launch_bounds__(64, 1)
void fa_scan_kernel(const float* __restrict__ x,
                    const float* __restrict__ vb,
                    const float* __restrict__ A,
                    const float* __restrict__ th,
                    const float* __restrict__ gain,
                    const float* __restrict__ tref,
                    float* __restrict__ emas,   // [nchunks][N]
                    int*   __restrict__ rins,   // [nchunks][N]
                    int B, int T, int F) {
#pragma clang fp contract(off)
    __shared__ float tile[2][TS][64];
    const int lane = threadIdx.x;
    const int gpb = F >> 6;                 // 64-feature groups per b
    const int bi = blockIdx.x;
    const int b = bi / gpb;
    const int f0 = (bi - b * gpb) << 6;
    const int f = f0 + lane;
    const int i = b * F + f;
    const int N = B * F;

    const float vbf = vb[f], Af = A[f], thf = th[f], gf = gain[f];
    const float alpha = 0.001f;             // f32(0.05/50)
    const int rs = (int)fmaxf(ceilf(tref[f] / 0.05f), 1.0f);

    const float* xb = x + (size_t)b * T * F + f0;  // [T][F] slice, cols f0..f0+63

    // staging layout: instr j covers rows 4j+srow, 16B at scol
    const int srow = lane >> 4;             // 0..3
    const int scol = (lane & 15) << 2;      // 0,4,...,60

    float4 stg[16];
    const int ntiles = T / TS;

    // ---- prologue: tile 0 -> regs -> LDS slot 0; tile 1 -> regs (in flight)
#pragma unroll
    for (int j = 0; j < 16; ++j)
        stg[j] = *(const float4*)&xb[(size_t)(4 * j + srow) * F + scol];
#pragma unroll
    for (int j = 0; j < 16; ++j)
        *(float4*)&tile[0][4 * j + srow][scol] = stg[j];
#pragma unroll
    for (int j = 0; j < 16; ++j)
        stg[j] = *(const float4*)&xb[(size_t)(TS + 4 * j + srow) * F + scol];

    float ema = 0.0f;
    int refc = 0;
    bool fastAll = __all((gf == 1.0f) && (Af == 1.0f) && (vbf == 0.0f));

    // dump chunk-0 seed (value for chunk 0 is ignored by K2's t==0 init,
    // but keep the reference zeros for tidiness)
    emas[i] = 0.0f;
    rins[i] = 0;

    // bit-exact t==0 seeding: ema = xt(0); general step then yields
    // fl(xt + alpha*0) = xt, so the steady-state loop needs no special case.
    ema = fastAll ? tile[0][0][lane] : (tile[0][0][lane] * gf);

    const int tiles_per_chunk = L_CHUNK / TS;

    for (int k = 0; k < ntiles; ++k) {
        const int slot = k & 1;
        if (k && (k & (tiles_per_chunk - 1)) == 0) {
            int c = k / tiles_per_chunk;
            emas[(size_t)c * N + i] = ema;
            rins[(size_t)c * N + i] = refc;
        }

        // ---- compute TS steps from LDS[slot], batches of 8 w/ prefetch
        float ra[8], rb[8];
#pragma unroll
        for (int j = 0; j < 8; ++j) ra[j] = tile[slot][j][lane];
        if (fastAll) {
#pragma unroll
            for (int t8 = 0; t8 < TS / 8; ++t8) {
                if (t8 < TS / 8 - 1) {
#pragma unroll
                    for (int j = 0; j < 8; ++j)
                        rb[j] = tile[slot][(t8 + 1) * 8 + j][lane];
                }
#pragma unroll
                for (int j = 0; j < 8; ++j) K1_STEP_FAST(ra[j]);
#pragma unroll
                for (int j = 0; j < 8; ++j) ra[j] = rb[j];
            }
        } else {
#pragma unroll
            for (int t8 = 0; t8 < TS / 8; ++t8) {
                if (t8 < TS / 8 - 1) {
#pragma unroll
                    for (int j = 0; j < 8; ++j)
                        rb[j] = tile[slot][(t8 + 1) * 8 + j][lane];
                }
#pragma unroll
                for (int j = 0; j < 8; ++j) K1_STEP_GEN(ra[j] * gf);
#pragma unroll
                for (int j = 0; j < 8; ++j) ra[j] = rb[j];
            }
        }

        // ---- commit tile k+1 regs -> LDS[slot^1]; issue loads for tile k+2
        if (k + 1 < ntiles) {
#pragma unroll
            for (int j = 0; j < 16; ++j)
                *(float4*)&tile[slot ^ 1][4 * j + srow][scol] = stg[j];
            if (k + 2 < ntiles) {
#pragma unroll
                for (int j = 0; j < 16; ++j)
                    stg[j] = *(const float4*)&xb[(size_t)((k + 2) * TS + 4 * j + srow) * F + scol];
            }
        }
    }
}

__global__ __launch_bounds__(256)
void fa_emit_kernel(const float* __restrict__ x,
                    const float* __restrict__ vb,
                    const float* __restrict__ A,
                    const float* __restrict__ th,
                    const float* __restrict__ gain,
                    const float* __restrict__ tref,
                    const float* __restrict__ emas,
                    const int*   __restrict__ rins,
                    float* __restrict__ out,
                    int B, int T, int F, int nchunks) {
#pragma clang fp contract(off)
    int N = B * F;
    int tid = blockIdx.x * blockDim.x + threadIdx.x;
    if (tid >= N * nchunks) return;
    int i = tid % N;
    int k = tid / N;
    int f = i % F;
    int b = i / F;
    const float vbf = vb[f], Af = A[f], thf = th[f], gf = gain[f];
    const float alpha = 0.001f;
    int rs = (int)fmaxf(ceilf(tref[f] / 0.05f), 1.0f);

    const float* xp = x + (size_t)b * T * F + f;
    float* va_out   = out + (size_t)b * (T + 1) * F + f;
    float* sp_out   = out + (size_t)B * (T + 1) * F + (size_t)b * (T + 1) * F + f;

    float ema = emas[tid];
    int refc  = rins[tid];
    float va_cand_;
    bool cross_, in_ref_, fired_;
    if (k == 0) va_out[0] = vbf;   // va_trace[:,0,:] = vb

    int tbeg = k * L_CHUNK;
    int tend = tbeg + L_CHUNK;
    if (tend > T) tend = T;

    float cur[K2_UNROLL], nxt[K2_UNROLL];
#pragma unroll
    for (int u = 0; u < K2_UNROLL; ++u) cur[u] = xp[(size_t)(tbeg + u) * F];

    float last_sp = 0.0f;
    for (int t0 = tbeg; t0 < tend; t0 += K2_UNROLL) {
        if (t0 + K2_UNROLL < tend) {
#pragma unroll
            for (int u = 0; u < K2_UNROLL; ++u)
                nxt[u] = xp[(size_t)(t0 + K2_UNROLL + u) * F];
        }
        bool first_blk = (t0 == 0);
#pragma unroll
        for (int u = 0; u < K2_UNROLL; ++u) {
            int t = t0 + u;
            float xt = cur[u] * gf;
            if (u == 0 && first_blk) FA_STEP_GEN(xt, true);
            else                     FA_STEP_GEN(xt, false);
            float va_next = (in_ref_ || fired_) ? vbf : va_cand_;
            float spv = fired_ ? 1.0f : 0.0f;
            va_out[(size_t)(t + 1) * F] = va_next;
            sp_out[(size_t)t * F] = spv;
            last_sp = spv;
        }
#pragma unroll
        for (int u = 0; u < K2_UNROLL; ++u) cur[u] = nxt[u];
    }
    if (tend == T) sp_out[(size_t)T * F] = last_sp;   // spikes[:,T,:] = fired_{T-1}
}

// Fallback: monolithic (used only if ws too small / shape odd).
__global__ __launch_bounds__(64, 1)
void fa_neuron_mono(const float* __restrict__ x,
                    const float* __restrict__ vb,
                    const float* __restrict__ A,
                    const float* __restrict__ th,
                    const float* __restrict__ gain,
                    const float* __restrict__ tref,
                    float* __restrict__ out,
                    int B, int T, int F) {
#pragma clang fp contract(off)
    int tid = blockIdx.x * blockDim.x + threadIdx.x;
    if (tid >= B * F) return;
    int f = tid % F;
    int b = tid / F;
    const float vbf = vb[f], Af = A[f], thf = th[f], gf = gain[f];
    const float alpha = 0.001f;
    int rs = (int)fmaxf(ceilf(tref[f] / 0.05f), 1.0f);
    const float* xp = x + (size_t)b * T * F + f;
    float* va_out   = out + (size_t)b * (T + 1) * F + f;
    float* sp_out   = out + (size_t)B * (T + 1) * F + (size_t)b * (T + 1) * F + f;
    va_out[0] = vbf;
    float ema = 0.0f;
    int refc = 0;
    float va_cand_;
    bool cross_, in_ref_, fired_;
    for (int t = 0; t < T; ++t) {
        float xt = xp[(size_t)t * F] * gf;
        if (t == 0) FA_STEP_GEN(xt, true);
        else        FA_STEP_GEN(xt, false);
        float va_next = (in_ref_ || fired_) ? vbf : va_cand_;
        float spv = fired_ ? 1.0f : 0.0f;
        va_out[(size_t)(t + 1) * F] = va_next;
        sp_out[(size_t)t * F] = spv;
        if (t == T - 1) sp_out[(size_t)T * F] = spv;
    }
}

extern "C" void kernel_launch(void* const* d_in, const int* in_sizes, int n_in,
                              void* d_out, int out_size, void* d_ws, size_t ws_size,
                              hipStream_t stream) {
    const float* x    = (const float*)d_in[0];
    const float* vb   = (const float*)d_in[1];
    const float* A    = (const float*)d_in[2];
    const float* th   = (const float*)d_in[3];
    const float* gain = (const float*)d_in[4];
    const float* tref = (const float*)d_in[5];
    float* out = (float*)d_out;

    int F = in_sizes[1];                                   // 512
    long long BF = (long long)out_size / 2 - in_sizes[0];  // B*F
    int B = (int)(BF / F);                                 // 16
    int T = (int)(in_sizes[0] / BF);                       // 4096
    int N = B * F;

    int nchunks = (T + L_CHUNK - 1) / L_CHUNK;
    size_t ws_need = (size_t)nchunks * N * (sizeof(float) + sizeof(int));

    bool tiled_ok = (ws_size >= ws_need) && (T % L_CHUNK == 0) &&
                    (T % TS == 0) && (T / TS >= 2) && (F % 64 == 0);

    if (!tiled_ok) {
        int block = 64;
        int grid = (N + block - 1) / block;
        fa_neuron_mono<<<grid, block, 0, stream>>>(x, vb, A, th, gain, tref, out, B, T, F);
        return;
    }

    float* emas = (float*)d_ws;
    int*   rins = (int*)(emas + (size_t)nchunks * N);

    {
        int block = 64;
        int grid = N / 64;   // one 64-chain group per block
        fa_scan_kernel<<<grid, block, 0, stream>>>(x, vb, A, th, gain, tref,
                                                   emas, rins, B, T, F);
    }
    {
        int total = N * nchunks;
        int block = 256;
        int grid = (total + block - 1) / block;
        fa_emit_kernel<<<grid, block, 0, stream>>>(x, vb, A, th, gain, tref,
                                                   emas, rins, out, B, T, F, nchunks);
    }
}

// Round 5
// 193.703 us; speedup vs baseline: 1.2827x; 1.2827x over previous
//
#include <hip/hip_runtime.h>
#include <stdint.h>

// FANeuron two-pass:
//  K1 (scan): sequential per-chain recurrence, compute-only. 64-thread block
//             = 64 chains (one b, 64 features). Depth-4 global_load_lds ring
//             with counted s_waitcnt vmcnt(32) -> loads for 2-3 future tiles
//             stay in flight across the whole loop (never drained to 0).
//             Refractory tracked as "next-ready step" nr (refc>0 <=> t<nr).
//  K2 (emit): one thread per (chain, chunk) replays its chunk bit-exactly
//             from the seeded (ema, nr) state and writes va_trace + spikes.

#define L_CHUNK 256
#define TS 64          // timesteps per K1 tile
#define DEPTH 4        // LDS ring depth
#define K2_UNROLL 8

typedef const __attribute__((address_space(1))) uint32_t* gptr_t;
typedef __attribute__((address_space(3))) uint32_t* lptr_t;

__global__ __launch_bounds__(64, 1)
void fa_scan_kernel(const float* __restrict__ x,
                    const float* __restrict__ vb,
                    const float* __restrict__ A,
                    const float* __restrict__ th,
                    const float* __restrict__ gain,
                    const float* __restrict__ tref,
                    float* __restrict__ emas,   // [nchunks][N] (c>=1 used)
                    int*   __restrict__ nrs,    // [nchunks][N] (c>=1 used)
                    int B, int T, int F) {
#pragma clang fp contract(off)
    __shared__ float lds[DEPTH][TS][64];
    const int lane = threadIdx.x;
    const int gpb = F >> 6;
    const int bi = blockIdx.x;
    const int b = bi / gpb;
    const int f0 = (bi - b * gpb) << 6;
    const int f = f0 + lane;
    const int i = b * F + f;
    const int N = B * F;

    const float vbf = vb[f], Af = A[f], thf = th[f], gf = gain[f];
    const float alpha = 0.001f;                 // f32(0.05/50)
    const int rs = (int)fmaxf(ceilf(tref[f] / 0.05f), 1.0f);

    const float* xb = x + (size_t)b * T * F + f0;
    // per-lane DMA source: lane l covers row (l>>4), 16B at col (l&15)*4
    const float* gsrc0 = xb + (size_t)(lane >> 4) * F + ((lane & 15) << 2);
    const int ntiles = T / TS;

    // issue tile j: 16 x global_load_lds_dwordx4 into slot j&(DEPTH-1).
    // LDS dest is wave-uniform; HW writes dest + lane*16 (linear, matches
    // [4 rows][16 lanes x 16B] per instruction).
#define ISSUE_TILE(J)                                                         \
    do {                                                                      \
        const float* s_ = gsrc0 + (size_t)(J) * TS * F;                       \
        float* d_ = &lds[(J) & (DEPTH - 1)][0][0];                            \
        _Pragma("unroll")                                                     \
        for (int jj = 0; jj < 16; ++jj) {                                     \
            __builtin_amdgcn_global_load_lds(                                 \
                (gptr_t)(s_ + (size_t)(4 * jj) * F),                          \
                (lptr_t)(d_ + 4 * jj * 64), 16, 0, 0);                        \
        }                                                                     \
    } while (0)

    ISSUE_TILE(0);
    ISSUE_TILE(1);
    ISSUE_TILE(2);

    bool fastAll = __all((gf == 1.0f) && (Af == 1.0f) && (vbf == 0.0f));

    float ema = 0.0f;
    int nr = 0;                                  // relative to current tile start

    for (int k = 0; k < ntiles; ++k) {
        // counted wait: tile k's 16 loads complete; up to 32 newer stay in flight
        if (k < ntiles - 2)       asm volatile("s_waitcnt vmcnt(32)" ::: "memory");
        else if (k == ntiles - 2) asm volatile("s_waitcnt vmcnt(16)" ::: "memory");
        else                      asm volatile("s_waitcnt vmcnt(0)"  ::: "memory");
        __builtin_amdgcn_sched_barrier(0);

        const float* tp = &lds[k & (DEPTH - 1)][0][lane];

        if (k == 0) {
            // bit-exact t==0 seeding: ema = xt(0); first step then yields
            // fl(xt + alpha*0) = xt, so no special case in the loop.
            float x0 = tp[0];
            ema = fastAll ? x0 : (x0 * gf);
        } else if ((k & 3) == 0) {               // L_CHUNK/TS == 4
            int c = k >> 2;
            emas[(size_t)c * N + i] = ema;
            nrs[(size_t)c * N + i] = nr + k * TS;  // absolute next-ready step
        }

        if (fastAll) {
#pragma unroll
            for (int t = 0; t < TS; ++t) {
                float xv = tp[t * 64];
                float d1 = xv - ema;
                float am = alpha * d1;
                ema = ema + am;
                float d2 = xv - ema;
                bool cross = fabsf(d2) >= thf;
                bool tge = t >= nr;
                bool fired = cross && tge;
                nr = fired ? (t + 1 + rs) : nr;
            }
        } else {
#pragma unroll
            for (int t = 0; t < TS; ++t) {
                float xt = tp[t * 64] * gf;
                float d1 = xt - ema;
                float am = alpha * d1;
                ema = ema + am;
                float d2 = xt - ema;
                float av = Af * d2;
                float vc = vbf - av;
                float dv = vc - vbf;
                bool cross = fabsf(dv) >= thf;
                bool tge = t >= nr;
                bool fired = cross && tge;
                nr = fired ? (t + 1 + rs) : nr;
            }
        }
        nr -= TS;                                // re-base to next tile

        if (k + 3 < ntiles) ISSUE_TILE(k + 3);
    }
#undef ISSUE_TILE
}

__global__ __launch_bounds__(256)
void fa_emit_kernel(const float* __restrict__ x,
                    const float* __restrict__ vb,
                    const float* __restrict__ A,
                    const float* __restrict__ th,
                    const float* __restrict__ gain,
                    const float* __restrict__ tref,
                    const float* __restrict__ emas,
                    const int*   __restrict__ nrs,
                    float* __restrict__ out,
                    int B, int T, int F, int nchunks) {
#pragma clang fp contract(off)
    int N = B * F;
    int tid = blockIdx.x * blockDim.x + threadIdx.x;
    if (tid >= N * nchunks) return;
    int i = tid % N;
    int k = tid / N;
    int f = i % F;
    int b = i / F;
    const float vbf = vb[f], Af = A[f], thf = th[f], gf = gain[f];
    const float alpha = 0.001f;
    int rs = (int)fmaxf(ceilf(tref[f] / 0.05f), 1.0f);

    const float* xp = x + (size_t)b * T * F + f;
    float* va_out   = out + (size_t)b * (T + 1) * F + f;
    float* sp_out   = out + (size_t)B * (T + 1) * F + (size_t)b * (T + 1) * F + f;

    int tbeg = k * L_CHUNK;
    int tend = tbeg + L_CHUNK;
    if (tend > T) tend = T;

    float cur[K2_UNROLL], nxt[K2_UNROLL];
#pragma unroll
    for (int u = 0; u < K2_UNROLL; ++u) cur[u] = xp[(size_t)(tbeg + u) * F];

    float ema;
    int nr;
    if (k == 0) {
        ema = cur[0] * gf;     // t==0 seeding trick (see K1)
        nr = 0;
        va_out[0] = vbf;       // va_trace[:,0,:] = vb
    } else {
        ema = emas[(size_t)k * N + i];
        nr = nrs[(size_t)k * N + i];
    }

    float last_sp = 0.0f;
    for (int t0 = tbeg; t0 < tend; t0 += K2_UNROLL) {
        if (t0 + K2_UNROLL < tend) {
#pragma unroll
            for (int u = 0; u < K2_UNROLL; ++u)
                nxt[u] = xp[(size_t)(t0 + K2_UNROLL + u) * F];
        }
#pragma unroll
        for (int u = 0; u < K2_UNROLL; ++u) {
            int t = t0 + u;
            float xt = cur[u] * gf;
            float d1 = xt - ema;
            float am = alpha * d1;
            ema = ema + am;
            float d2 = xt - ema;
            float av = Af * d2;
            float vc = vbf - av;       // va_cand
            float dv = vc - vbf;
            bool cross = fabsf(dv) >= thf;
            bool tge = t >= nr;
            bool fired = cross && tge;
            float va_next = (cross || !tge) ? vbf : vc;
            nr = fired ? (t + 1 + rs) : nr;
            float spv = fired ? 1.0f : 0.0f;
            va_out[(size_t)(t + 1) * F] = va_next;
            sp_out[(size_t)t * F] = spv;
            last_sp = spv;
        }
#pragma unroll
        for (int u = 0; u < K2_UNROLL; ++u) cur[u] = nxt[u];
    }
    if (tend == T) sp_out[(size_t)T * F] = last_sp;   // spikes[:,T,:] = fired_{T-1}
}

// Fallback: monolithic (used only if ws too small / shape odd).
__global__ __launch_bounds__(64, 1)
void fa_neuron_mono(const float* __restrict__ x,
                    const float* __restrict__ vb,
                    const float* __restrict__ A,
                    const float* __restrict__ th,
                    const float* __restrict__ gain,
                    const float* __restrict__ tref,
                    float* __restrict__ out,
                    int B, int T, int F) {
#pragma clang fp contract(off)
    int tid = blockIdx.x * blockDim.x + threadIdx.x;
    if (tid >= B * F) return;
    int f = tid % F;
    int b = tid / F;
    const float vbf = vb[f], Af = A[f], thf = th[f], gf = gain[f];
    const float alpha = 0.001f;
    int rs = (int)fmaxf(ceilf(tref[f] / 0.05f), 1.0f);
    const float* xp = x + (size_t)b * T * F + f;
    float* va_out   = out + (size_t)b * (T + 1) * F + f;
    float* sp_out   = out + (size_t)B * (T + 1) * F + (size_t)b * (T + 1) * F + f;
    va_out[0] = vbf;
    float ema = 0.0f;
    int nr = 0;
    for (int t = 0; t < T; ++t) {
        float xt = xp[(size_t)t * F] * gf;
        if (t == 0) {
            ema = xt;
        } else {
            float d1 = xt - ema;
            float am = alpha * d1;
            ema = ema + am;
        }
        float d2 = xt - ema;
        float av = Af * d2;
        float vc = vbf - av;
        float dv = vc - vbf;
        bool cross = fabsf(dv) >= thf;
        bool tge = t >= nr;
        bool fired = cross && tge;
        float va_next = (cross || !tge) ? vbf : vc;
        nr = fired ? (t + 1 + rs) : nr;
        float spv = fired ? 1.0f : 0.0f;
        va_out[(size_t)(t + 1) * F] = va_next;
        sp_out[(size_t)t * F] = spv;
        if (t == T - 1) sp_out[(size_t)T * F] = spv;
    }
}

extern "C" void kernel_launch(void* const* d_in, const int* in_sizes, int n_in,
                              void* d_out, int out_size, void* d_ws, size_t ws_size,
                              hipStream_t stream) {
    const float* x    = (const float*)d_in[0];
    const float* vb   = (const float*)d_in[1];
    const float* A    = (const float*)d_in[2];
    const float* th   = (const float*)d_in[3];
    const float* gain = (const float*)d_in[4];
    const float* tref = (const float*)d_in[5];
    float* out = (float*)d_out;

    int F = in_sizes[1];                                   // 512
    long long BF = (long long)out_size / 2 - in_sizes[0];  // B*F
    int B = (int)(BF / F);                                 // 16
    int T = (int)(in_sizes[0] / BF);                       // 4096
    int N = B * F;

    int nchunks = (T + L_CHUNK - 1) / L_CHUNK;
    size_t ws_need = (size_t)nchunks * N * (sizeof(float) + sizeof(int));

    bool tiled_ok = (ws_size >= ws_need) && (T % L_CHUNK == 0) &&
                    (T % TS == 0) && (T / TS >= 4) && (F % 64 == 0) &&
                    (L_CHUNK == 4 * TS);

    if (!tiled_ok) {
        int block = 64;
        int grid = (N + block - 1) / block;
        fa_neuron_mono<<<grid, block, 0, stream>>>(x, vb, A, th, gain, tref, out, B, T, F);
        return;
    }

    float* emas = (float*)d_ws;
    int*   nrs  = (int*)(emas + (size_t)nchunks * N);

    {
        int block = 64;
        int grid = N / 64;   // one 64-chain group per block
        fa_scan_kernel<<<grid, block, 0, stream>>>(x, vb, A, th, gain, tref,
                                                   emas, nrs, B, T, F);
    }
    {
        int total = N * nchunks;
        int block = 256;
        int grid = (total + block - 1) / block;
        fa_emit_kernel<<<grid, block, 0, stream>>>(x, vb, A, th, gain, tref,
                                                   emas, nrs, out, B, T, F, nchunks);
    }
}

// Round 6
// 178.098 us; speedup vs baseline: 1.3951x; 1.0876x over previous
//
#include <hip/hip_runtime.h>
#include <stdint.h>

// FANeuron two-pass:
//  K1 (scan): sequential per-chain recurrence, compute-only. 64-thread block
//             = 64 chains (one b, 64 features). Depth-4 global_load_lds ring,
//             counted s_waitcnt vmcnt(32) (2-3 future tiles always in flight,
//             never drained). Inner loop: ping-pong batches of 8 ds_reads so
//             LDS latency hides under the previous batch's compute.
//             Refractory tracked as "next-ready step" nr (refc>0 <=> t<nr).
//  K2 (emit): one thread per (chain, chunk) replays its chunk bit-exactly
//             from the seeded (ema, nr) state and writes va_trace + spikes.

#define L_CHUNK 256
#define TS 64          // timesteps per K1 tile
#define DEPTH 4        // LDS ring depth
#define K2_UNROLL 8

typedef const __attribute__((address_space(1))) uint32_t* gptr_t;
typedef __attribute__((address_space(3))) uint32_t* lptr_t;

__global__ __launch_bounds__(64, 1)
void fa_scan_kernel(const float* __restrict__ x,
                    const float* __restrict__ vb,
                    const float* __restrict__ A,
                    const float* __restrict__ th,
                    const float* __restrict__ gain,
                    const float* __restrict__ tref,
                    float* __restrict__ emas,   // [nchunks][N] (c>=1 used)
                    int*   __restrict__ nrs,    // [nchunks][N] (c>=1 used)
                    int B, int T, int F) {
#pragma clang fp contract(off)
    __shared__ float lds[DEPTH][TS][64];
    const int lane = threadIdx.x;
    const int gpb = F >> 6;
    const int bi = blockIdx.x;
    const int b = bi / gpb;
    const int f0 = (bi - b * gpb) << 6;
    const int f = f0 + lane;
    const int i = b * F + f;
    const int N = B * F;

    const float vbf = vb[f], Af = A[f], thf = th[f], gf = gain[f];
    const float alpha = 0.001f;                 // f32(0.05/50)
    const int rs = (int)fmaxf(ceilf(tref[f] / 0.05f), 1.0f);

    const float* xb = x + (size_t)b * T * F + f0;
    // per-lane DMA source: lane l covers row (l>>4), 16B at col (l&15)*4
    const float* gsrc0 = xb + (size_t)(lane >> 4) * F + ((lane & 15) << 2);
    const int ntiles = T / TS;

    // issue tile j: 16 x global_load_lds_dwordx4 into slot j&(DEPTH-1).
    // LDS dest is wave-uniform; HW writes dest + lane*16 (linear, matches
    // [4 rows][16 lanes x 16B] per instruction).
#define ISSUE_TILE(J)                                                         \
    do {                                                                      \
        const float* s_ = gsrc0 + (size_t)(J) * TS * F;                       \
        float* d_ = &lds[(J) & (DEPTH - 1)][0][0];                            \
        _Pragma("unroll")                                                     \
        for (int jj = 0; jj < 16; ++jj) {                                     \
            __builtin_amdgcn_global_load_lds(                                 \
                (gptr_t)(s_ + (size_t)(4 * jj) * F),                          \
                (lptr_t)(d_ + 4 * jj * 64), 16, 0, 0);                        \
        }                                                                     \
    } while (0)

    ISSUE_TILE(0);
    ISSUE_TILE(1);
    ISSUE_TILE(2);

    bool fastAll = __all((gf == 1.0f) && (Af == 1.0f) && (vbf == 0.0f));

    float ema = 0.0f;
    int nr = 0;                                  // relative to current tile start

    for (int k = 0; k < ntiles; ++k) {
        // counted wait: tile k's 16 loads complete; up to 32 newer stay in
        // flight (vmcnt retires in order; seed stores fold in harmlessly).
        if (k < ntiles - 2)       asm volatile("s_waitcnt vmcnt(32)" ::: "memory");
        else if (k == ntiles - 2) asm volatile("s_waitcnt vmcnt(16)" ::: "memory");
        else                      asm volatile("s_waitcnt vmcnt(0)"  ::: "memory");
        __builtin_amdgcn_sched_barrier(0);

        const int slot = k & (DEPTH - 1);

        if (k == 0) {
            // bit-exact t==0 seeding: ema = xt(0); first step then yields
            // fl(xt + alpha*0) = xt, so no special case in the loop.
            float x0 = lds[0][0][lane];
            ema = fastAll ? x0 : (x0 * gf);
        } else if ((k & 3) == 0) {               // L_CHUNK/TS == 4
            int c = k >> 2;
            emas[(size_t)c * N + i] = ema;
            nrs[(size_t)c * N + i] = nr + k * TS;  // absolute next-ready step
        }

        // ---- ping-pong batches of 8: LDS latency hides under compute
        float ra[8], rb[8];
#pragma unroll
        for (int j = 0; j < 8; ++j) ra[j] = lds[slot][j][lane];

        if (fastAll) {
#pragma unroll
            for (int t8 = 0; t8 < TS / 8; ++t8) {
                if (t8 < TS / 8 - 1) {
#pragma unroll
                    for (int j = 0; j < 8; ++j)
                        rb[j] = lds[slot][(t8 + 1) * 8 + j][lane];
                }
#pragma unroll
                for (int j = 0; j < 8; ++j) {
                    const int t = t8 * 8 + j;
                    float xv = ra[j];
                    float d1 = xv - ema;
                    float am = alpha * d1;
                    ema = ema + am;
                    float d2 = xv - ema;
                    bool cross = fabsf(d2) >= thf;
                    bool tge = t >= nr;
                    bool fired = cross && tge;
                    nr = fired ? (t + 1 + rs) : nr;
                }
#pragma unroll
                for (int j = 0; j < 8; ++j) ra[j] = rb[j];
            }
        } else {
#pragma unroll
            for (int t8 = 0; t8 < TS / 8; ++t8) {
                if (t8 < TS / 8 - 1) {
#pragma unroll
                    for (int j = 0; j < 8; ++j)
                        rb[j] = lds[slot][(t8 + 1) * 8 + j][lane];
                }
#pragma unroll
                for (int j = 0; j < 8; ++j) {
                    const int t = t8 * 8 + j;
                    float xt = ra[j] * gf;
                    float d1 = xt - ema;
                    float am = alpha * d1;
                    ema = ema + am;
                    float d2 = xt - ema;
                    float av = Af * d2;
                    float vc = vbf - av;
                    float dv = vc - vbf;
                    bool cross = fabsf(dv) >= thf;
                    bool tge = t >= nr;
                    bool fired = cross && tge;
                    nr = fired ? (t + 1 + rs) : nr;
                }
#pragma unroll
                for (int j = 0; j < 8; ++j) ra[j] = rb[j];
            }
        }
        nr -= TS;                                // re-base to next tile

        if (k + 3 < ntiles) ISSUE_TILE(k + 3);
    }
#undef ISSUE_TILE
}

__global__ __launch_bounds__(256)
void fa_emit_kernel(const float* __restrict__ x,
                    const float* __restrict__ vb,
                    const float* __restrict__ A,
                    const float* __restrict__ th,
                    const float* __restrict__ gain,
                    const float* __restrict__ tref,
                    const float* __restrict__ emas,
                    const int*   __restrict__ nrs,
                    float* __restrict__ out,
                    int B, int T, int F, int nchunks) {
#pragma clang fp contract(off)
    int N = B * F;
    int tid = blockIdx.x * blockDim.x + threadIdx.x;
    if (tid >= N * nchunks) return;
    int i = tid % N;
    int k = tid / N;
    int f = i % F;
    int b = i / F;
    const float vbf = vb[f], Af = A[f], thf = th[f], gf = gain[f];
    const float alpha = 0.001f;
    int rs = (int)fmaxf(ceilf(tref[f] / 0.05f), 1.0f);

    const float* xp = x + (size_t)b * T * F + f;
    float* va_out   = out + (size_t)b * (T + 1) * F + f;
    float* sp_out   = out + (size_t)B * (T + 1) * F + (size_t)b * (T + 1) * F + f;

    int tbeg = k * L_CHUNK;
    int tend = tbeg + L_CHUNK;
    if (tend > T) tend = T;

    float cur[K2_UNROLL], nxt[K2_UNROLL];
#pragma unroll
    for (int u = 0; u < K2_UNROLL; ++u) cur[u] = xp[(size_t)(tbeg + u) * F];

    float ema;
    int nr;
    if (k == 0) {
        ema = cur[0] * gf;     // t==0 seeding trick (see K1)
        nr = 0;
        va_out[0] = vbf;       // va_trace[:,0,:] = vb
    } else {
        ema = emas[(size_t)k * N + i];
        nr = nrs[(size_t)k * N + i];
    }

    float last_sp = 0.0f;
    for (int t0 = tbeg; t0 < tend; t0 += K2_UNROLL) {
        if (t0 + K2_UNROLL < tend) {
#pragma unroll
            for (int u = 0; u < K2_UNROLL; ++u)
                nxt[u] = xp[(size_t)(t0 + K2_UNROLL + u) * F];
        }
#pragma unroll
        for (int u = 0; u < K2_UNROLL; ++u) {
            int t = t0 + u;
            float xt = cur[u] * gf;
            float d1 = xt - ema;
            float am = alpha * d1;
            ema = ema + am;
            float d2 = xt - ema;
            float av = Af * d2;
            float vc = vbf - av;       // va_cand
            float dv = vc - vbf;
            bool cross = fabsf(dv) >= thf;
            bool tge = t >= nr;
            bool fired = cross && tge;
            float va_next = (cross || !tge) ? vbf : vc;
            nr = fired ? (t + 1 + rs) : nr;
            float spv = fired ? 1.0f : 0.0f;
            va_out[(size_t)(t + 1) * F] = va_next;
            sp_out[(size_t)t * F] = spv;
            last_sp = spv;
        }
#pragma unroll
        for (int u = 0; u < K2_UNROLL; ++u) cur[u] = nxt[u];
    }
    if (tend == T) sp_out[(size_t)T * F] = last_sp;   // spikes[:,T,:] = fired_{T-1}
}

// Fallback: monolithic (used only if ws too small / shape odd).
__global__ __launch_bounds__(64, 1)
void fa_neuron_mono(const float* __restrict__ x,
                    const float* __restrict__ vb,
                    const float* __restrict__ A,
                    const float* __restrict__ th,
                    const float* __restrict__ gain,
                    const float* __restrict__ tref,
                    float* __restrict__ out,
                    int B, int T, int F) {
#pragma clang fp contract(off)
    int tid = blockIdx.x * blockDim.x + threadIdx.x;
    if (tid >= B * F) return;
    int f = tid % F;
    int b = tid / F;
    const float vbf = vb[f], Af = A[f], thf = th[f], gf = gain[f];
    const float alpha = 0.001f;
    int rs = (int)fmaxf(ceilf(tref[f] / 0.05f), 1.0f);
    const float* xp = x + (size_t)b * T * F + f;
    float* va_out   = out + (size_t)b * (T + 1) * F + f;
    float* sp_out   = out + (size_t)B * (T + 1) * F + (size_t)b * (T + 1) * F + f;
    va_out[0] = vbf;
    float ema = 0.0f;
    int nr = 0;
    for (int t = 0; t < T; ++t) {
        float xt = xp[(size_t)t * F] * gf;
        if (t == 0) {
            ema = xt;
        } else {
            float d1 = xt - ema;
            float am = alpha * d1;
            ema = ema + am;
        }
        float d2 = xt - ema;
        float av = Af * d2;
        float vc = vbf - av;
        float dv = vc - vbf;
        bool cross = fabsf(dv) >= thf;
        bool tge = t >= nr;
        bool fired = cross && tge;
        float va_next = (cross || !tge) ? vbf : vc;
        nr = fired ? (t + 1 + rs) : nr;
        float spv = fired ? 1.0f : 0.0f;
        va_out[(size_t)(t + 1) * F] = va_next;
        sp_out[(size_t)t * F] = spv;
        if (t == T - 1) sp_out[(size_t)T * F] = spv;
    }
}

extern "C" void kernel_launch(void* const* d_in, const int* in_sizes, int n_in,
                              void* d_out, int out_size, void* d_ws, size_t ws_size,
                              hipStream_t stream) {
    const float* x    = (const float*)d_in[0];
    const float* vb   = (const float*)d_in[1];
    const float* A    = (const float*)d_in[2];
    const float* th   = (const float*)d_in[3];
    const float* gain = (const float*)d_in[4];
    const float* tref = (const float*)d_in[5];
    float* out = (float*)d_out;

    int F = in_sizes[1];                                   // 512
    long long BF = (long long)out_size / 2 - in_sizes[0];  // B*F
    int B = (int)(BF / F);                                 // 16
    int T = (int)(in_sizes[0] / BF);                       // 4096
    int N = B * F;

    int nchunks = (T + L_CHUNK - 1) / L_CHUNK;
    size_t ws_need = (size_t)nchunks * N * (sizeof(float) + sizeof(int));

    bool tiled_ok = (ws_size >= ws_need) && (T % L_CHUNK == 0) &&
                    (T % TS == 0) && (T / TS >= 4) && (F % 64 == 0) &&
                    (L_CHUNK == 4 * TS);

    if (!tiled_ok) {
        int block = 64;
        int grid = (N + block - 1) / block;
        fa_neuron_mono<<<grid, block, 0, stream>>>(x, vb, A, th, gain, tref, out, B, T, F);
        return;
    }

    float* emas = (float*)d_ws;
    int*   nrs  = (int*)(emas + (size_t)nchunks * N);

    {
        int block = 64;
        int grid = N / 64;   // one 64-chain group per block
        fa_scan_kernel<<<grid, block, 0, stream>>>(x, vb, A, th, gain, tref,
                                                   emas, nrs, B, T, F);
    }
    {
        int total = N * nchunks;
        int block = 256;
        int grid = (total + block - 1) / block;
        fa_emit_kernel<<<grid, block, 0, stream>>>(x, vb, A, th, gain, tref,
                                                   emas, nrs, out, B, T, F, nchunks);
    }
}